// Round 6
// baseline (425.327 us; speedup 1.0000x reference)
//
#include <hip/hip_runtime.h>

// Bilinear spatial-transformer sampling.
// image: [B=32, H=256, W=256, C=32] f32 (NHWC), theta: [B,6] f32
// out:   [B, 256, 256, 32] f32
//
// Mapping: 1 thread = 1 float4 channel-group of TWO output pixels
// (rows ho and ho+128, same column). 8 consecutive lanes cover one pixel's
// 32 channels -> each corner gather is a 128B contiguous segment; with
// near-identity theta the whole wave's gather per corner is ~1.1KB nearly
// contiguous. 8 independent loads/thread for memory-level parallelism.
//
// Block = 256 threads = 32 pixel-columns of one row(-pair); 8 blocks per
// row => default round-robin blockIdx%8 -> XCD equals the x-strip index,
// so each XCD's L2 sees a fixed 32-column input strip (vertical corner
// reuse stays XCD-local). Do not change this mapping.

#define OUT_H 256
#define OUT_W 256
#define IMG_H 256
#define IMG_W 256
#define NCH   32
#define NB    32

typedef float f32x4 __attribute__((ext_vector_type(4)));

__global__ __launch_bounds__(256) void stn_bilinear_kernel(
    const float* __restrict__ img,
    const float* __restrict__ theta,
    float* __restrict__ out)
{
    int gid = blockIdx.x * 256 + threadIdx.x;   // [0, B*128*W*8)
    int cg  = gid & 7;                          // float4 channel group
    int q   = gid >> 3;                         // pixel index (half grid)
    int wo  = q & (OUT_W - 1);
    int ho  = (q >> 8) & 127;                   // row in [0,128)
    int b   = q >> 15;                          // batch (block-uniform)

    // batch is wave-uniform -> scalarize theta loads (s_load, not 64 v-loads)
    int bu = __builtin_amdgcn_readfirstlane(b);
    const float* t = theta + bu * 6;
    float t0 = t[0], t1 = t[1], t2 = t[2], t3 = t[3], t4 = t[4], t5 = t[5];

    const float step = 2.0f / 255.0f;           // linspace(-1,1,256) step
    float xn = fmaf((float)wo, step, -1.0f);

    const f32x4* imgv = (const f32x4*)img + (size_t)bu * (IMG_H * IMG_W * (NCH / 4));
    f32x4* outv = (f32x4*)out;

    // ---- per-pixel address/weight math for both rows (h=0: ho, h=1: ho+128)
    float wa[2], wb[2], wc[2], wd[2];
    unsigned ia[2], ib[2], ic[2], id[2], oi[2];
    #pragma unroll
    for (int h = 0; h < 2; ++h) {
        int hoh = ho + h * 128;
        float yn = fmaf((float)hoh, step, -1.0f);
        float sx = t0 * xn + t1 * yn + t2;
        float sy = t3 * xn + t4 * yn + t5;
        float x = 0.5f * (sx + 1.0f) * (float)IMG_W;
        float y = 0.5f * (sy + 1.0f) * (float)IMG_H;
        int x0 = (int)x, y0 = (int)y;           // trunc-toward-zero (ref)
        int x1 = x0 + 1, y1 = y0 + 1;
        x0 = min(max(x0, 0), IMG_W - 1);
        x1 = min(max(x1, 0), IMG_W - 1);
        y0 = min(max(y0, 0), IMG_H - 1);
        y1 = min(max(y1, 0), IMG_H - 1);
        // weights from CLIPPED corner coords (matches reference)
        float x0f = (float)x0, x1f = (float)x1;
        float y0f = (float)y0, y1f = (float)y1;
        wa[h] = (x1f - x) * (y1f - y);
        wb[h] = (x1f - x) * (y - y0f);
        wc[h] = (x - x0f) * (y1f - y);
        wd[h] = (x - x0f) * (y - y0f);
        unsigned r0 = (unsigned)(y0 * IMG_W) * (NCH / 4);
        unsigned r1 = (unsigned)(y1 * IMG_W) * (NCH / 4);
        unsigned c0 = (unsigned)x0 * (NCH / 4) + cg;
        unsigned c1 = (unsigned)x1 * (NCH / 4) + cg;
        ia[h] = r0 + c0;  ib[h] = r1 + c0;
        ic[h] = r0 + c1;  id[h] = r1 + c1;
        oi[h] = (unsigned)(((b * OUT_H + hoh) * OUT_W + wo) * 8 + cg);
    }

    // ---- issue all 8 gathers before consuming (MLP)
    f32x4 pa0 = imgv[ia[0]], pb0 = imgv[ib[0]], pc0 = imgv[ic[0]], pd0 = imgv[id[0]];
    f32x4 pa1 = imgv[ia[1]], pb1 = imgv[ib[1]], pc1 = imgv[ic[1]], pd1 = imgv[id[1]];

    f32x4 o0 = wa[0] * pa0 + wb[0] * pb0 + wc[0] * pc0 + wd[0] * pd0;
    f32x4 o1 = wa[1] * pa1 + wb[1] * pb1 + wc[1] * pc1 + wd[1] * pd1;

    // output is write-once: bypass cache retention so gather rows keep L2
    __builtin_nontemporal_store(o0, &outv[oi[0]]);
    __builtin_nontemporal_store(o1, &outv[oi[1]]);
}

extern "C" void kernel_launch(void* const* d_in, const int* in_sizes, int n_in,
                              void* d_out, int out_size, void* d_ws, size_t ws_size,
                              hipStream_t stream)
{
    const float* img   = (const float*)d_in[0];
    const float* theta = (const float*)d_in[1];
    float* out = (float*)d_out;

    // threads = B * (H/2 rows) * W * (C/4 groups) = 32*128*256*8 = 8,388,608
    int total = NB * (OUT_H / 2) * OUT_W * (NCH / 4);
    int blocks = total / 256;   // 32768
    stn_bilinear_kernel<<<blocks, 256, 0, stream>>>(img, theta, out);
}

// Round 10
// 415.104 us; speedup vs baseline: 1.0246x; 1.0246x over previous
//
#include <hip/hip_runtime.h>

// Bilinear spatial-transformer sampling.
// image: [B=32, H=256, W=256, C=32] f32 (NHWC), theta: [B,6] f32
// out:   [B, 256, 256, 32] f32
//
// Mapping: 1 thread = 1 float4 channel-group of TWO ADJACENT-ROW output
// pixels (rows 2r and 2r+1, same column). Adjacent rows share the middle
// input row (y1 of px0 == y0 of px1 typically) -> gathers hit the same
// 128B lines back-to-back in one thread (L1 hit), and the per-block input
// footprint halves vs the previous (ho, ho+128) pairing.
//
// Block = 256 threads = 32 pixel-columns of one row-pair; 8 blocks per
// row-pair => default round-robin blockIdx%8 -> XCD equals the x-strip
// index, so each XCD's L2 sees a fixed 32-column input strip (vertical
// corner reuse stays XCD-local). Do not change this mapping.

#define OUT_H 256
#define OUT_W 256
#define IMG_H 256
#define IMG_W 256
#define NCH   32
#define NB    32

typedef float f32x4 __attribute__((ext_vector_type(4)));

__global__ __launch_bounds__(256) void stn_bilinear_kernel(
    const float* __restrict__ img,
    const float* __restrict__ theta,
    float* __restrict__ out)
{
    int gid = blockIdx.x * 256 + threadIdx.x;   // [0, B*128*W*8)
    int cg  = gid & 7;                          // float4 channel group
    int q   = gid >> 3;                         // row-pair-pixel index
    int wo  = q & (OUT_W - 1);
    int r   = (q >> 8) & 127;                   // row-pair in [0,128)
    int b   = q >> 15;                          // batch (block-uniform)

    // batch is wave-uniform -> scalarize theta loads (s_load, not 64 v-loads)
    int bu = __builtin_amdgcn_readfirstlane(b);
    const float* t = theta + bu * 6;
    float t0 = t[0], t1 = t[1], t2 = t[2], t3 = t[3], t4 = t[4], t5 = t[5];

    const float step = 2.0f / 255.0f;           // linspace(-1,1,256) step
    float xn = fmaf((float)wo, step, -1.0f);

    const f32x4* imgv = (const f32x4*)img + (size_t)bu * (IMG_H * IMG_W * (NCH / 4));
    f32x4* outv = (f32x4*)out;

    // ---- per-pixel address/weight math for rows 2r (h=0) and 2r+1 (h=1)
    float wa[2], wb[2], wc[2], wd[2];
    unsigned ia[2], ib[2], ic[2], id[2], oi[2];
    #pragma unroll
    for (int h = 0; h < 2; ++h) {
        int hoh = 2 * r + h;
        float yn = fmaf((float)hoh, step, -1.0f);
        float sx = t0 * xn + t1 * yn + t2;
        float sy = t3 * xn + t4 * yn + t5;
        float x = 0.5f * (sx + 1.0f) * (float)IMG_W;
        float y = 0.5f * (sy + 1.0f) * (float)IMG_H;
        int x0 = (int)x, y0 = (int)y;           // trunc-toward-zero (ref)
        int x1 = x0 + 1, y1 = y0 + 1;
        x0 = min(max(x0, 0), IMG_W - 1);
        x1 = min(max(x1, 0), IMG_W - 1);
        y0 = min(max(y0, 0), IMG_H - 1);
        y1 = min(max(y1, 0), IMG_H - 1);
        // weights from CLIPPED corner coords (matches reference)
        float x0f = (float)x0, x1f = (float)x1;
        float y0f = (float)y0, y1f = (float)y1;
        wa[h] = (x1f - x) * (y1f - y);
        wb[h] = (x1f - x) * (y - y0f);
        wc[h] = (x - x0f) * (y1f - y);
        wd[h] = (x - x0f) * (y - y0f);
        unsigned r0 = (unsigned)(y0 * IMG_W) * (NCH / 4);
        unsigned r1 = (unsigned)(y1 * IMG_W) * (NCH / 4);
        unsigned c0 = (unsigned)x0 * (NCH / 4) + cg;
        unsigned c1 = (unsigned)x1 * (NCH / 4) + cg;
        ia[h] = r0 + c0;  ib[h] = r1 + c0;
        ic[h] = r0 + c1;  id[h] = r1 + c1;
        oi[h] = (unsigned)(((b * OUT_H + hoh) * OUT_W + wo) * 8 + cg);
    }

    // ---- issue all 8 gathers before consuming (MLP)
    f32x4 pa0 = imgv[ia[0]], pb0 = imgv[ib[0]], pc0 = imgv[ic[0]], pd0 = imgv[id[0]];
    f32x4 pa1 = imgv[ia[1]], pb1 = imgv[ib[1]], pc1 = imgv[ic[1]], pd1 = imgv[id[1]];

    f32x4 o0 = wa[0] * pa0 + wb[0] * pb0 + wc[0] * pc0 + wd[0] * pd0;
    f32x4 o1 = wa[1] * pa1 + wb[1] * pb1 + wc[1] * pc1 + wd[1] * pd1;

    // output is write-once: bypass cache retention so gather rows keep L2
    __builtin_nontemporal_store(o0, &outv[oi[0]]);
    __builtin_nontemporal_store(o1, &outv[oi[1]]);
}

extern "C" void kernel_launch(void* const* d_in, const int* in_sizes, int n_in,
                              void* d_out, int out_size, void* d_ws, size_t ws_size,
                              hipStream_t stream)
{
    const float* img   = (const float*)d_in[0];
    const float* theta = (const float*)d_in[1];
    float* out = (float*)d_out;

    // threads = B * (H/2 row-pairs) * W * (C/4 groups) = 32*128*256*8
    int total = NB * (OUT_H / 2) * OUT_W * (NCH / 4);
    int blocks = total / 256;   // 32768
    stn_bilinear_kernel<<<blocks, 256, 0, stream>>>(img, theta, out);
}

// Round 11
// 411.557 us; speedup vs baseline: 1.0335x; 1.0086x over previous
//
#include <hip/hip_runtime.h>

// Bilinear spatial-transformer sampling.
// image: [B=32, H=256, W=256, C=32] f32 (NHWC), theta: [B,6] f32
// out:   [B, 256, 256, 32] f32
//
// Mapping: 1 thread = 1 float4 channel-group of TWO ADJACENT-ROW output
// pixels (rows 2r and 2r+1, same column). Adjacent rows share the middle
// input row (y1 of px0 == y0 of px1 typically) -> gathers hit the same
// 128B lines back-to-back in one thread (L1 hit); measured -10us vs the
// (ho, ho+128) pairing (r6->r10 A/B).
//
// Block = 256 threads = 32 pixel-columns of one row-pair; 8 blocks per
// row-pair => default round-robin blockIdx%8 -> XCD equals the x-strip
// index, so each XCD's L2 sees a fixed 32-column input strip (vertical
// corner reuse stays XCD-local). Do not change this mapping.
//
// R10 change (single lever): plain stores instead of nontemporal —
// isolating the never-measured NT-store choice from round 1. NT forfeits
// L2 write-coalescing; the input strip working set (~2MB/XCD) leaves L2
// room for a write-back stream.

#define OUT_H 256
#define OUT_W 256
#define IMG_H 256
#define IMG_W 256
#define NCH   32
#define NB    32

typedef float f32x4 __attribute__((ext_vector_type(4)));

__global__ __launch_bounds__(256) void stn_bilinear_kernel(
    const float* __restrict__ img,
    const float* __restrict__ theta,
    float* __restrict__ out)
{
    int gid = blockIdx.x * 256 + threadIdx.x;   // [0, B*128*W*8)
    int cg  = gid & 7;                          // float4 channel group
    int q   = gid >> 3;                         // row-pair-pixel index
    int wo  = q & (OUT_W - 1);
    int r   = (q >> 8) & 127;                   // row-pair in [0,128)
    int b   = q >> 15;                          // batch (block-uniform)

    // batch is wave-uniform -> scalarize theta loads (s_load, not 64 v-loads)
    int bu = __builtin_amdgcn_readfirstlane(b);
    const float* t = theta + bu * 6;
    float t0 = t[0], t1 = t[1], t2 = t[2], t3 = t[3], t4 = t[4], t5 = t[5];

    const float step = 2.0f / 255.0f;           // linspace(-1,1,256) step
    float xn = fmaf((float)wo, step, -1.0f);

    const f32x4* imgv = (const f32x4*)img + (size_t)bu * (IMG_H * IMG_W * (NCH / 4));
    f32x4* outv = (f32x4*)out;

    // ---- per-pixel address/weight math for rows 2r (h=0) and 2r+1 (h=1)
    float wa[2], wb[2], wc[2], wd[2];
    unsigned ia[2], ib[2], ic[2], id[2], oi[2];
    #pragma unroll
    for (int h = 0; h < 2; ++h) {
        int hoh = 2 * r + h;
        float yn = fmaf((float)hoh, step, -1.0f);
        float sx = t0 * xn + t1 * yn + t2;
        float sy = t3 * xn + t4 * yn + t5;
        float x = 0.5f * (sx + 1.0f) * (float)IMG_W;
        float y = 0.5f * (sy + 1.0f) * (float)IMG_H;
        int x0 = (int)x, y0 = (int)y;           // trunc-toward-zero (ref)
        int x1 = x0 + 1, y1 = y0 + 1;
        x0 = min(max(x0, 0), IMG_W - 1);
        x1 = min(max(x1, 0), IMG_W - 1);
        y0 = min(max(y0, 0), IMG_H - 1);
        y1 = min(max(y1, 0), IMG_H - 1);
        // weights from CLIPPED corner coords (matches reference)
        float x0f = (float)x0, x1f = (float)x1;
        float y0f = (float)y0, y1f = (float)y1;
        wa[h] = (x1f - x) * (y1f - y);
        wb[h] = (x1f - x) * (y - y0f);
        wc[h] = (x - x0f) * (y1f - y);
        wd[h] = (x - x0f) * (y - y0f);
        unsigned r0 = (unsigned)(y0 * IMG_W) * (NCH / 4);
        unsigned r1 = (unsigned)(y1 * IMG_W) * (NCH / 4);
        unsigned c0 = (unsigned)x0 * (NCH / 4) + cg;
        unsigned c1 = (unsigned)x1 * (NCH / 4) + cg;
        ia[h] = r0 + c0;  ib[h] = r1 + c0;
        ic[h] = r0 + c1;  id[h] = r1 + c1;
        oi[h] = (unsigned)(((b * OUT_H + hoh) * OUT_W + wo) * 8 + cg);
    }

    // ---- issue all 8 gathers before consuming (MLP)
    f32x4 pa0 = imgv[ia[0]], pb0 = imgv[ib[0]], pc0 = imgv[ic[0]], pd0 = imgv[id[0]];
    f32x4 pa1 = imgv[ia[1]], pb1 = imgv[ib[1]], pc1 = imgv[ic[1]], pd1 = imgv[id[1]];

    f32x4 o0 = wa[0] * pa0 + wb[0] * pb0 + wc[0] * pc0 + wd[0] * pd0;
    f32x4 o1 = wa[1] * pa1 + wb[1] * pb1 + wc[1] * pc1 + wd[1] * pd1;

    // R10: plain coalesced stores (isolating the NT-store lever)
    outv[oi[0]] = o0;
    outv[oi[1]] = o1;
}

extern "C" void kernel_launch(void* const* d_in, const int* in_sizes, int n_in,
                              void* d_out, int out_size, void* d_ws, size_t ws_size,
                              hipStream_t stream)
{
    const float* img   = (const float*)d_in[0];
    const float* theta = (const float*)d_in[1];
    float* out = (float*)d_out;

    // threads = B * (H/2 row-pairs) * W * (C/4 groups) = 32*128*256*8
    int total = NB * (OUT_H / 2) * OUT_W * (NCH / 4);
    int blocks = total / 256;   // 32768
    stn_bilinear_kernel<<<blocks, 256, 0, stream>>>(img, theta, out);
}